// Round 2
// baseline (12672.899 us; speedup 1.0000x reference)
//
#include <hip/hip_runtime.h>

// InputFeedRNNDecoder on MI355X.  T=100 B=64 S=602 H=1024 E=512 V=10000.
// Plan A (ws >= ~126MB): precompute M2 = M @ W_attn once (bf16 MFMA GEMM,
//   staged from f32 mem), per step: gates0, gates1, align(M2), ctx_f32, out.
// Plan B (smaller ws): no M2; per step adds qproj (nh1 @ W_attn^T), align and
//   ctx read f32 memory_bank directly.
// Weights bf16-packed [k/32][n][32]; h/feed states bf16; c states f32.

#define DI __device__ __forceinline__

typedef __attribute__((ext_vector_type(4))) short s4v;
typedef __attribute__((ext_vector_type(8))) short s8v;
typedef __attribute__((ext_vector_type(4))) float f4v;

DI float b2f(short u) {
  unsigned int x = ((unsigned int)(unsigned short)u) << 16;
  float f; __builtin_memcpy(&f, &x, 4); return f;
}
DI short f2b(float f) {  // round-to-nearest-even
  unsigned int x; __builtin_memcpy(&x, &f, 4);
  return (short)((x + 0x7fffu + ((x >> 16) & 1u)) >> 16);
}
DI s8v cat8(s4v lo, s4v hi) {
  s8v r; r[0]=lo[0];r[1]=lo[1];r[2]=lo[2];r[3]=lo[3];
  r[4]=hi[0];r[5]=hi[1];r[6]=hi[2];r[7]=hi[3]; return r;
}
DI f4v mfma16(s8v a, s8v b, f4v c) {
  return __builtin_amdgcn_mfma_f32_16x16x32_bf16(a, b, c, 0, 0, 0);
}
DI float sigm(float x) { return 1.f / (1.f + __expf(-x)); }

// ---------------- packing kernels (run once per launch) --------------------

// dst[(kt*N + n)*32 + k32] = W[n][kt*32+k32]  with W = [WA | WB] along k.
__global__ void pack_w(const float* __restrict__ WA, int Ka,
                       const float* __restrict__ WB, int Kb,
                       short* __restrict__ dst, int N, long total) {
  long i = (long)blockIdx.x * blockDim.x + threadIdx.x;
  long stride = (long)gridDim.x * blockDim.x;
  for (; i < total; i += stride) {
    int c = (int)(i & 3);
    long r = i >> 2;
    int n = (int)(r % N);
    int kt = (int)(r / N);
    int k = kt * 32 + c * 8;
    const float* s = (k < Ka) ? (WA + (size_t)n * Ka + k)
                              : (WB + (size_t)n * Kb + (k - Ka));
    s8v o;
    #pragma unroll
    for (int j = 0; j < 8; ++j) o[j] = f2b(s[j]);
    *(s8v*)(dst + r * 32 + c * 8) = o;
  }
}

// dst[(kt*1024 + n)*32 + k32] = W[kt*32+k32][n]   (B[k][n] = W_attn[k][n])
__global__ void pack_wT(const float* __restrict__ W, short* __restrict__ dst) {
  long i = (long)blockIdx.x * blockDim.x + threadIdx.x;
  if (i >= 1048576) return;
  int k32 = (int)(i & 31);
  long r = i >> 5;
  int n = (int)(r & 1023);
  int kt = (int)(r >> 10);
  dst[i] = f2b(W[(size_t)(kt * 32 + k32) * 1024 + n]);
}

__global__ __launch_bounds__(64) void emb_gather(const int* __restrict__ tgt,
                                                 const float* __restrict__ emb,
                                                 short* __restrict__ dst) {
  int tb = blockIdx.x;                // 0..6399 = t*64+b
  int idx = tgt[tb];
  const float* s = emb + (size_t)idx * 512 + threadIdx.x * 8;
  s8v o;
  #pragma unroll
  for (int j = 0; j < 8; ++j) o[j] = f2b(s[j]);
  *(s8v*)(dst + (size_t)tb * 512 + threadIdx.x * 8) = o;
}

__global__ void init_state(const float* __restrict__ h0, const float* __restrict__ c0,
                           short* __restrict__ h0b, short* __restrict__ h1b,
                           float* __restrict__ c0buf, float* __restrict__ c1buf,
                           short* __restrict__ feedb) {
  int i = blockIdx.x * 256 + threadIdx.x;
  if (i < 65536) {
    h0b[i] = f2b(h0[i]);
    h1b[i] = f2b(h0[65536 + i]);
    c0buf[i] = c0[i];
    c1buf[i] = c0[65536 + i];
    feedb[i] = 0;   // bf16 zero
  }
}

// ---------- M2 = mem(f32->bf16) @ W_attn  (38528 x 1024 x 1024) ------------

__global__ __launch_bounds__(256) void m2_gemm_f32(const float* __restrict__ memf,
                                                   const short* __restrict__ Wap,
                                                   short* __restrict__ M2) {
  __shared__ short As[128][40];
  __shared__ short Bs[64][40];
  int row0 = blockIdx.x * 128, n0 = blockIdx.y * 64;
  int tid = threadIdx.x;
  int w = tid >> 6, l = tid & 63, r15 = l & 15, g = l >> 4;
  f4v z = {0.f, 0.f, 0.f, 0.f};
  f4v acc[2][4];
  #pragma unroll
  for (int i = 0; i < 2; ++i)
    #pragma unroll
    for (int j = 0; j < 4; ++j) acc[i][j] = z;
  for (int kt = 0; kt < 32; ++kt) {
    __syncthreads();
    #pragma unroll
    for (int i = 0; i < 2; ++i) {
      int cid = tid + 256 * i;
      int rr = cid >> 2, c4 = cid & 3;
      const float* s = memf + (size_t)(row0 + rr) * 1024 + kt * 32 + c4 * 8;
      f4v u0 = *(const f4v*)s, u1 = *(const f4v*)(s + 4);
      s8v o;
      #pragma unroll
      for (int j = 0; j < 4; ++j) { o[j] = f2b(u0[j]); o[4 + j] = f2b(u1[j]); }
      *(s8v*)&As[rr][c4 * 8] = o;
    }
    {
      int rr = tid >> 2, c4 = tid & 3;
      *(s8v*)&Bs[rr][c4 * 8] =
          *(const s8v*)(Wap + ((size_t)kt * 1024 + n0 + rr) * 32 + c4 * 8);
    }
    __syncthreads();
    s8v af[2];
    #pragma unroll
    for (int rf = 0; rf < 2; ++rf) {
      const short* ap = &As[w * 32 + rf * 16 + r15][4 * g];
      af[rf] = cat8(*(const s4v*)ap, *(const s4v*)(ap + 16));
    }
    #pragma unroll
    for (int cf = 0; cf < 4; ++cf) {
      const short* bp = &Bs[cf * 16 + r15][4 * g];
      s8v bf = cat8(*(const s4v*)bp, *(const s4v*)(bp + 16));
      acc[0][cf] = mfma16(af[0], bf, acc[0][cf]);
      acc[1][cf] = mfma16(af[1], bf, acc[1][cf]);
    }
  }
  #pragma unroll
  for (int rf = 0; rf < 2; ++rf)
    #pragma unroll
    for (int cf = 0; cf < 4; ++cf)
      #pragma unroll
      for (int q = 0; q < 4; ++q) {
        int row = row0 + w * 32 + rf * 16 + g * 4 + q;
        int col = n0 + cf * 16 + r15;
        M2[(size_t)row * 1024 + col] = f2b(acc[rf][cf][q]);
      }
}

// ---------------- per-step GEMM core ---------------------------------------

template <int NG>
DI void kloop(const short* __restrict__ A, int ld, int nkt,
              const short* __restrict__ Wp, size_t wkt,
              f4v* acc, int rA, int g) {
  if (nkt <= 0) return;
  const short* ap = A + (size_t)rA * ld + 4 * g;
  s4v alo = *(const s4v*)ap, ahi = *(const s4v*)(ap + 16);
  s4v blo[NG], bhi[NG];
  #pragma unroll
  for (int t = 0; t < NG; ++t) {
    blo[t] = *(const s4v*)(Wp + (size_t)t * 32768);
    bhi[t] = *(const s4v*)(Wp + (size_t)t * 32768 + 16);
  }
  for (int kt = 0; kt < nkt - 1; ++kt) {
    const short* apn = ap + (kt + 1) * 32;
    const short* bpn = Wp + (size_t)(kt + 1) * wkt;
    s4v nalo = *(const s4v*)apn, nahi = *(const s4v*)(apn + 16);
    s4v nblo[NG], nbhi[NG];
    #pragma unroll
    for (int t = 0; t < NG; ++t) {
      nblo[t] = *(const s4v*)(bpn + (size_t)t * 32768);
      nbhi[t] = *(const s4v*)(bpn + (size_t)t * 32768 + 16);
    }
    s8v a = cat8(alo, ahi);
    #pragma unroll
    for (int t = 0; t < NG; ++t) acc[t] = mfma16(a, cat8(blo[t], bhi[t]), acc[t]);
    alo = nalo; ahi = nahi;
    #pragma unroll
    for (int t = 0; t < NG; ++t) { blo[t] = nblo[t]; bhi[t] = nbhi[t]; }
  }
  s8v a = cat8(alo, ahi);
  #pragma unroll
  for (int t = 0; t < NG; ++t) acc[t] = mfma16(a, cat8(blo[t], bhi[t]), acc[t]);
}

// Gates GEMM + LSTM cell epilogue. Grid 256 x 64thr.
__global__ __launch_bounds__(64) void gate_gemm(
    const short* __restrict__ Wpack,
    const short* __restrict__ A0, int ld0, int nkt0,
    const short* __restrict__ A1, int ld1, int nkt1,
    const short* __restrict__ A2, int ld2, int nkt2,
    const float* __restrict__ bi, const float* __restrict__ bh,
    float* __restrict__ cbuf,
    short* __restrict__ hout0, short* __restrict__ hout1) {
  int bid = blockIdx.x;
  int rt = bid & 3, cs = bid >> 2;
  int l = threadIdx.x, r15 = l & 15, g = l >> 4;
  int rA = rt * 16 + r15;
  int nb = cs * 16 + r15;
  f4v z = {0.f, 0.f, 0.f, 0.f};
  f4v acc[4] = {z, z, z, z};
  const size_t wkt = (size_t)4096 * 32;
  const short* wbase = Wpack + (size_t)nb * 32 + 4 * g;
  kloop<4>(A0, ld0, nkt0, wbase, wkt, acc, rA, g);
  kloop<4>(A1, ld1, nkt1, wbase + (size_t)nkt0 * wkt, wkt, acc, rA, g);
  kloop<4>(A2, ld2, nkt2, wbase + (size_t)(nkt0 + nkt1) * wkt, wkt, acc, rA, g);
  int h = nb;
  float bs0 = bi[h] + bh[h];
  float bs1 = bi[1024 + h] + bh[1024 + h];
  float bs2 = bi[2048 + h] + bh[2048 + h];
  float bs3 = bi[3072 + h] + bh[3072 + h];
  #pragma unroll
  for (int q = 0; q < 4; ++q) {
    int brow = rt * 16 + g * 4 + q;
    size_t off = (size_t)brow * 1024 + h;
    float iv = acc[0][q] + bs0;
    float fv = acc[1][q] + bs1;
    float gv = acc[2][q] + bs2;
    float ov = acc[3][q] + bs3;
    float cn = sigm(fv) * cbuf[off] + sigm(iv) * tanhf(gv);
    float hn = sigm(ov) * tanhf(cn);
    cbuf[off] = cn;
    short hb = f2b(hn);
    hout0[off] = hb;
    if (hout1) hout1[off] = hb;
  }
}

// Out projection + tanh. Grid 256 x 64thr. N=1024, K=2048 (ctx | nh1).
__global__ __launch_bounds__(64) void out_gemm(
    const short* __restrict__ Wpack,
    const short* __restrict__ Actx, const short* __restrict__ Anh1,
    float* __restrict__ outp, short* __restrict__ feedn) {
  int bid = blockIdx.x;
  int rt = bid & 3, cs = bid >> 2;
  int l = threadIdx.x, r15 = l & 15, g = l >> 4;
  int rA = rt * 16 + r15, nb = cs * 16 + r15;
  f4v z = {0.f, 0.f, 0.f, 0.f};
  f4v acc[1] = {z};
  const size_t wkt = (size_t)1024 * 32;
  const short* wbase = Wpack + (size_t)nb * 32 + 4 * g;
  kloop<1>(Actx, 1024, 32, wbase, wkt, acc, rA, g);
  kloop<1>(Anh1, 1024, 32, wbase + 32 * wkt, wkt, acc, rA, g);
  #pragma unroll
  for (int q = 0; q < 4; ++q) {
    int brow = rt * 16 + g * 4 + q;
    size_t off = (size_t)brow * 1024 + nb;
    float v = tanhf(acc[0][q]);
    outp[off] = v;
    feedn[off] = f2b(v);
  }
}

// q = nh1 @ W_attn^T   (plan B). Grid 256 x 64thr, N=1024, K=1024.
__global__ __launch_bounds__(64) void qproj_gemm(
    const short* __restrict__ Wpack, const short* __restrict__ Anh1,
    short* __restrict__ qb) {
  int bid = blockIdx.x;
  int rt = bid & 3, cs = bid >> 2;
  int l = threadIdx.x, r15 = l & 15, g = l >> 4;
  int rA = rt * 16 + r15, nb = cs * 16 + r15;
  f4v z = {0.f, 0.f, 0.f, 0.f};
  f4v acc[1] = {z};
  const size_t wkt = (size_t)1024 * 32;
  const short* wbase = Wpack + (size_t)nb * 32 + 4 * g;
  kloop<1>(Anh1, 1024, 32, wbase, wkt, acc, rA, g);
  #pragma unroll
  for (int q = 0; q < 4; ++q) {
    int brow = rt * 16 + g * 4 + q;
    qb[(size_t)brow * 1024 + nb] = f2b(acc[0][q]);
  }
}

// ---------------- attention ------------------------------------------------

// align[b][s] = nh1[b] . M2[s][b]   (plan A)  grid (64,151) x 256thr
__global__ __launch_bounds__(256) void align_dot_m2(const short* __restrict__ nh1,
                                                    const short* __restrict__ M2,
                                                    float* __restrict__ alg) {
  int b = blockIdx.x;
  int s = blockIdx.y * 4 + (threadIdx.x >> 6);
  int l = threadIdx.x & 63;
  if (s >= 602) return;
  const short* m2 = M2 + ((size_t)s * 64 + b) * 1024 + l * 16;
  const short* nh = nh1 + (size_t)b * 1024 + l * 16;
  s8v m0 = *(const s8v*)m2, m1 = *(const s8v*)(m2 + 8);
  s8v q0 = *(const s8v*)nh, q1 = *(const s8v*)(nh + 8);
  float sum = 0.f;
  #pragma unroll
  for (int j = 0; j < 8; ++j)
    sum += b2f(m0[j]) * b2f(q0[j]) + b2f(m1[j]) * b2f(q1[j]);
  #pragma unroll
  for (int o = 32; o; o >>= 1) sum += __shfl_down(sum, o);
  if (l == 0) alg[b * 602 + s] = sum;
}

// align[b][s] = q[b] . mem[s][b]   (plan B)  grid (64,151) x 256thr
__global__ __launch_bounds__(256) void align_dot_f32(const short* __restrict__ qb,
                                                     const float* __restrict__ memf,
                                                     float* __restrict__ alg) {
  int b = blockIdx.x;
  int s = blockIdx.y * 4 + (threadIdx.x >> 6);
  int l = threadIdx.x & 63;
  if (s >= 602) return;
  const float* mp = memf + ((size_t)s * 64 + b) * 1024 + l * 16;
  const short* qp = qb + (size_t)b * 1024 + l * 16;
  f4v m0 = *(const f4v*)mp, m1 = *(const f4v*)(mp + 4);
  f4v m2 = *(const f4v*)(mp + 8), m3 = *(const f4v*)(mp + 12);
  s8v q0 = *(const s8v*)qp, q1 = *(const s8v*)(qp + 8);
  float sum = 0.f;
  #pragma unroll
  for (int j = 0; j < 4; ++j) {
    sum += m0[j] * b2f(q0[j]) + m1[j] * b2f(q0[4 + j]);
    sum += m2[j] * b2f(q1[j]) + m3[j] * b2f(q1[4 + j]);
  }
  #pragma unroll
  for (int o = 32; o; o >>= 1) sum += __shfl_down(sum, o);
  if (l == 0) alg[b * 602 + s] = sum;
}

// softmax over S + ctx = a.M (f32 mem) + attns write.  grid (64,8) x 256thr.
__global__ __launch_bounds__(256) void ctx_softmax_f32(const float* __restrict__ alg,
                                                       const float* __restrict__ memf,
                                                       short* __restrict__ ctxb,
                                                       float* __restrict__ attns) {
  __shared__ float p[602];
  __shared__ float red[2048];
  __shared__ float rtmp[8];
  int b = blockIdx.x, hc = blockIdx.y;
  int tid = threadIdx.x;
  const float* al = alg + b * 602;
  float lm = -1e30f;
  for (int i = tid; i < 602; i += 256) { float v = al[i]; p[i] = v; lm = fmaxf(lm, v); }
  #pragma unroll
  for (int o = 32; o; o >>= 1) lm = fmaxf(lm, __shfl_down(lm, o));
  if ((tid & 63) == 0) rtmp[tid >> 6] = lm;
  __syncthreads();
  float m = fmaxf(fmaxf(rtmp[0], rtmp[1]), fmaxf(rtmp[2], rtmp[3]));
  float ls = 0.f;
  for (int i = tid; i < 602; i += 256) { float e = __expf(p[i] - m); p[i] = e; ls += e; }
  #pragma unroll
  for (int o = 32; o; o >>= 1) ls += __shfl_down(ls, o);
  if ((tid & 63) == 0) rtmp[4 + (tid >> 6)] = ls;
  __syncthreads();
  float invZ = 1.f / (rtmp[4] + rtmp[5] + rtmp[6] + rtmp[7]);
  int cg = tid & 15, sg = tid >> 4;
  float a8[8] = {0, 0, 0, 0, 0, 0, 0, 0};
  for (int s = sg; s < 602; s += 16) {
    float wv = p[s];
    const float* mp = memf + ((size_t)s * 64 + b) * 1024 + hc * 128 + cg * 8;
    f4v v0 = *(const f4v*)mp, v1 = *(const f4v*)(mp + 4);
    #pragma unroll
    for (int j = 0; j < 4; ++j) { a8[j] += wv * v0[j]; a8[4 + j] += wv * v1[j]; }
  }
  #pragma unroll
  for (int j = 0; j < 8; ++j) red[sg * 128 + cg * 8 + j] = a8[j];
  __syncthreads();
  if (tid < 128) {
    float t0 = 0.f;
    #pragma unroll
    for (int g2 = 0; g2 < 16; ++g2) t0 += red[g2 * 128 + tid];
    ctxb[(size_t)b * 1024 + hc * 128 + tid] = f2b(t0 * invZ);
  }
  if (hc == 0) {
    for (int i = tid; i < 602; i += 256) attns[b * 602 + i] = p[i] * invZ;
  }
}

// ---------------- launcher -------------------------------------------------

extern "C" void kernel_launch(void* const* d_in, const int* in_sizes, int n_in,
                              void* d_out, int out_size, void* d_ws, size_t ws_size,
                              hipStream_t stream) {
  const int*   tgt  = (const int*)  d_in[0];
  const float* mem  = (const float*)d_in[1];
  const float* h0   = (const float*)d_in[2];
  const float* c0   = (const float*)d_in[3];
  const float* embw = (const float*)d_in[4];
  const float* Wi0  = (const float*)d_in[5];
  const float* Wh0  = (const float*)d_in[6];
  const float* bi0  = (const float*)d_in[7];
  const float* bh0  = (const float*)d_in[8];
  const float* Wi1  = (const float*)d_in[9];
  const float* Wh1  = (const float*)d_in[10];
  const float* bi1  = (const float*)d_in[11];
  const float* bh1  = (const float*)d_in[12];
  const float* Wat  = (const float*)d_in[13];
  const float* Wou  = (const float*)d_in[14];
  float* out = (float*)d_out;

  auto a256 = [](size_t x) { return (x + 255) & ~(size_t)255; };
  const size_t MBE = (size_t)602 * 64 * 1024;
  // plan selection (small buffers first in layout)
  size_t commonBytes = 8 * a256(65536 * 2)        // bf16 state buffers
                     + 2 * a256(65536 * 4)        // c states
                     + a256((size_t)64 * 602 * 4) // alg
                     + a256((size_t)100 * 64 * 512 * 2)  // emba
                     + a256((size_t)64 * 1024 * 32 * 2)  // Wop
                     + a256((size_t)64 * 4096 * 32 * 2)  // W1p
                     + a256((size_t)80 * 4096 * 32 * 2); // W0p
  size_t planAExtra = a256((size_t)32 * 1024 * 32 * 2) + a256(MBE * 2);   // Wap + M2
  bool planA = ws_size >= commonBytes + planAExtra;

  char* base = (char*)d_ws;
  size_t off = 0;
  auto alloc = [&](size_t bytes) -> void* {
    void* p = base + off;
    off += (bytes + 255) & ~(size_t)255;
    return p;
  };
  // small, per-step-written buffers first
  short* feedb0 = (short*)alloc(65536 * 2);
  short* feedb1 = (short*)alloc(65536 * 2);
  short* h0b0 = (short*)alloc(65536 * 2);
  short* h0b1 = (short*)alloc(65536 * 2);
  short* h1b0 = (short*)alloc(65536 * 2);
  short* h1b1 = (short*)alloc(65536 * 2);
  short* nh0  = (short*)alloc(65536 * 2);
  short* ctxb = (short*)alloc(65536 * 2);
  float* c0b  = (float*)alloc(65536 * 4);
  float* c1b  = (float*)alloc(65536 * 4);
  float* alg  = (float*)alloc((size_t)64 * 602 * 4);
  short* emba = (short*)alloc((size_t)100 * 64 * 512 * 2);
  short* Wop  = (short*)alloc((size_t)64 * 1024 * 32 * 2);
  short* W1p  = (short*)alloc((size_t)64 * 4096 * 32 * 2);
  short* W0p  = (short*)alloc((size_t)80 * 4096 * 32 * 2);
  short* Wap = nullptr;  // plan A: W_attn packed col-major; plan B: row-major
  short* M2 = nullptr;
  short* qb = nullptr;
  if (planA) {
    Wap = (short*)alloc((size_t)32 * 1024 * 32 * 2);
    M2  = (short*)alloc(MBE * 2);
  } else {
    Wap = (short*)alloc((size_t)32 * 1024 * 32 * 2);
    qb  = (short*)alloc(65536 * 2);
  }
  short* feedb[2] = {feedb0, feedb1};
  short* h0b[2] = {h0b0, h0b1};
  short* h1b[2] = {h1b0, h1b1};

  hipLaunchKernelGGL(emb_gather, dim3(6400), dim3(64), 0, stream, tgt, embw, emba);
  hipLaunchKernelGGL(pack_w, dim3(2048), dim3(256), 0, stream, Wi0, 1536, Wh0, 1024,
                     W0p, 4096, (long)80 * 4096 * 4);
  hipLaunchKernelGGL(pack_w, dim3(2048), dim3(256), 0, stream, Wi1, 1024, Wh1, 1024,
                     W1p, 4096, (long)64 * 4096 * 4);
  hipLaunchKernelGGL(pack_w, dim3(1024), dim3(256), 0, stream, Wou, 2048, Wou, 2048,
                     Wop, 1024, (long)64 * 1024 * 4);
  hipLaunchKernelGGL(init_state, dim3(256), dim3(256), 0, stream, h0, c0,
                     h0b[0], h1b[0], c0b, c1b, feedb[0]);
  if (planA) {
    hipLaunchKernelGGL(pack_wT, dim3(4096), dim3(256), 0, stream, Wat, Wap);
    hipLaunchKernelGGL(m2_gemm_f32, dim3(301, 16), dim3(256), 0, stream, mem, Wap, M2);
  } else {
    hipLaunchKernelGGL(pack_w, dim3(512), dim3(256), 0, stream, Wat, 1024, Wat, 1024,
                       Wap, 1024, (long)32 * 1024 * 4);
  }

  for (int t = 0; t < 100; ++t) {
    int cur = t & 1, nxt = cur ^ 1;
    hipLaunchKernelGGL(gate_gemm, dim3(256), dim3(64), 0, stream,
                       W0p,
                       emba + (size_t)t * 64 * 512, 512, 16,
                       feedb[cur], 1024, 32,
                       h0b[cur], 1024, 32,
                       bi0, bh0, c0b, nh0, h0b[nxt]);
    hipLaunchKernelGGL(gate_gemm, dim3(256), dim3(64), 0, stream,
                       W1p,
                       nh0, 1024, 32,
                       h1b[cur], 1024, 32,
                       h1b[cur], 1024, 0,
                       bi1, bh1, c1b, h1b[nxt], (short*)nullptr);
    if (planA) {
      hipLaunchKernelGGL(align_dot_m2, dim3(64, 151), dim3(256), 0, stream,
                         h1b[nxt], M2, alg);
    } else {
      hipLaunchKernelGGL(qproj_gemm, dim3(256), dim3(64), 0, stream,
                         Wap, h1b[nxt], qb);
      hipLaunchKernelGGL(align_dot_f32, dim3(64, 151), dim3(256), 0, stream,
                         qb, mem, alg);
    }
    hipLaunchKernelGGL(ctx_softmax_f32, dim3(64, 8), dim3(256), 0, stream,
                       alg, mem, ctxb, out + 6553600 + (size_t)t * 64 * 602);
    hipLaunchKernelGGL(out_gemm, dim3(256), dim3(64), 0, stream,
                       Wop, ctxb, h1b[nxt],
                       out + (size_t)t * 65536, feedb[nxt]);
  }
}